// Round 6
// baseline (196.734 us; speedup 1.0000x reference)
//
#include <hip/hip_runtime.h>

// ---------------------------------------------------------------------------
// DTP_5377299055222: SE(3)-equivariant conv block, B=1, N=8192, K=32, H=16
// f32 in / f32 out.
// R5 -> R6: B still spilled ~134 floats/thread at 128 VGPR (fully-unrolled
// i*o*f loops -> compiler pipelines dozens of dot16 LDS loads -> schedule
// pressure >> live set). Fix structurally: FOUR single-pair kernels
// (k_p00/k_p01/k_p10/k_p11), each staging only its own weight blob (6-10 KB)
// and carrying a ~60-100 float live set. All __launch_bounds__(256,2)=128.
// ---------------------------------------------------------------------------

#define NNODE 8192
#define KNBR  32

// workspace float offsets
#define XI0_OFF   0         // 8192*16
#define XJ0_OFF   131072
#define XI1_OFF   262144    // 8192*24
#define XJ1_OFF   458752
#define INT0_OFF  655360    // 8192*16
#define INT1_OFF  786432    // 8192*24
#define WTS_OFF   983040    // 7328 floats
#define FLAG_OFF  990400    // 1 int

// radial weight blob per pair: [w1 16][b1 16][g1 16][b2 16][g2 16][b3 C][w2t 256][w3t 16C]
// = 336 + 17C floats.  Order 00,01,10,11 ; C = 128,64,64,96.
#define BASE00 0
#define BASE01 2512
#define BASE10 3936
#define BASE11 5360
#define SZ00 2512
#define SZ01 1424
#define SZ10 1424
#define SZ11 1968

static __device__ __forceinline__ float fsilu(float x) {
    return x * (1.0f / (1.0f + __expf(-x)));
}

static __device__ __forceinline__ float dot16(const float* __restrict__ w, const float* h) {
    const float4* w4 = (const float4*)w;
    float4 a = w4[0], b = w4[1], c = w4[2], d = w4[3];
    float s0 = a.x * h[0];  s0 = fmaf(a.y, h[1], s0);  s0 = fmaf(a.z, h[2],  s0);  s0 = fmaf(a.w, h[3],  s0);
    float s1 = b.x * h[4];  s1 = fmaf(b.y, h[5], s1);  s1 = fmaf(b.z, h[6],  s1);  s1 = fmaf(b.w, h[7],  s1);
    float s2 = c.x * h[8];  s2 = fmaf(c.y, h[9], s2);  s2 = fmaf(c.z, h[10], s2);  s2 = fmaf(c.w, h[11], s2);
    float s3 = d.x * h[12]; s3 = fmaf(d.y, h[13], s3); s3 = fmaf(d.z, h[14], s3);  s3 = fmaf(d.w, h[15], s3);
    return (s0 + s1) + (s2 + s3);
}

static __device__ __forceinline__ void ln16ip(float* x, const float* __restrict__ g) {
    float mu = 0.f;
#pragma unroll
    for (int h = 0; h < 16; ++h) mu += x[h];
    mu *= 0.0625f;
    float var = 0.f;
#pragma unroll
    for (int h = 0; h < 16; ++h) { float d = x[h] - mu; var = fmaf(d, d, var); }
    var *= 0.0625f;
    const float s = rsqrtf(var + 1e-5f);
#pragma unroll
    for (int h = 0; h < 16; ++h) x[h] = (x[h] - mu) * s * g[h];
}

// radial MLP layers 1+2 (incl. both LayerNorms). w = blob base (LDS).
template <int C>
static __device__ __forceinline__ void radial16(float dist, const float* __restrict__ w, float* hh) {
    float t[16];
#pragma unroll
    for (int h = 0; h < 16; ++h) t[h] = fsilu(fmaf(dist, w[h], w[16 + h]));
    ln16ip(t, w + 32);
    const float* w2t = w + 80 + C;
#pragma unroll
    for (int e = 0; e < 16; ++e) hh[e] = fsilu(w[48 + e] + dot16(w2t + e * 16, t));
    ln16ip(hh, w + 64);
}

// stage `cnt4` float4s from src into LDS
static __device__ __forceinline__ void stage(float4* dst, const float* __restrict__ src, int cnt4) {
    const float4* g4 = (const float4*)src;
    for (int i = threadIdx.x; i < cnt4; i += 256) dst[i] = g4[i];
}

// ---------------------------------------------------------------------------
__global__ __launch_bounds__(256) void k_lin_in(
    const float* __restrict__ x0, const float* __restrict__ x1,
    const float* __restrict__ wxi0, const float* __restrict__ wxj0,
    const float* __restrict__ wxi1, const float* __restrict__ wxj1,
    float* __restrict__ xi0, float* __restrict__ xj0,
    float* __restrict__ xi1, float* __restrict__ xj1) {
    const int t = blockIdx.x * 256 + threadIdx.x;  // 131072 threads
    const int n = t >> 4, e = t & 15;
    const float* xr = x0 + n * 16;
    float si = 0.f, sj = 0.f;
#pragma unroll
    for (int d = 0; d < 16; ++d) {
        const float xv = xr[d];
        si = fmaf(xv, wxi0[d * 16 + e], si);
        sj = fmaf(xv, wxj0[d * 16 + e], sj);
    }
    xi0[t] = si; xj0[t] = sj;
    if (e < 8) {
        const float* x1r = x1 + n * 24;
#pragma unroll
        for (int m = 0; m < 3; ++m) {
            float a = 0.f, b = 0.f;
#pragma unroll
            for (int d = 0; d < 8; ++d) {
                const float xv = x1r[d * 3 + m];
                a = fmaf(xv, wxi1[d * 8 + e], a);
                b = fmaf(xv, wxj1[d * 8 + e], b);
            }
            xi1[n * 24 + e * 3 + m] = a;
            xj1[n * 24 + e * 3 + m] = b;
        }
    }
}

// ---------------------------------------------------------------------------
struct RPtrs { const float* a[32]; };  // input order: 00,10,01,11 x (w1,b1,g1,w2,b2,g2,w3,b3)

__global__ void k_wts(RPtrs rp, const unsigned char* __restrict__ maskb,
                      float* __restrict__ wts, int* __restrict__ flagp) {
    const int tid = threadIdx.x;
    const int Cs[4]  = {128, 64, 64, 96};                 // blob order 00,01,10,11
    const int bas[4] = {BASE00, BASE01, BASE10, BASE11};
    const int rpi[4] = {0, 2, 1, 3};                      // d_in group for each blob slot
#pragma unroll
    for (int pp = 0; pp < 4; ++pp) {
        const int C = Cs[pp];
        float* dst = wts + bas[pp];
        const float* w1 = rp.a[rpi[pp] * 8 + 0]; const float* b1 = rp.a[rpi[pp] * 8 + 1];
        const float* g1 = rp.a[rpi[pp] * 8 + 2]; const float* w2 = rp.a[rpi[pp] * 8 + 3];
        const float* b2 = rp.a[rpi[pp] * 8 + 4]; const float* g2 = rp.a[rpi[pp] * 8 + 5];
        const float* w3 = rp.a[rpi[pp] * 8 + 6]; const float* b3 = rp.a[rpi[pp] * 8 + 7];
        if (tid < 16) {
            dst[tid] = w1[tid]; dst[16 + tid] = b1[tid]; dst[32 + tid] = g1[tid];
            dst[48 + tid] = b2[tid]; dst[64 + tid] = g2[tid];
        }
        for (int i = tid; i < C; i += 256) dst[80 + i] = b3[i];
        { const int e = tid >> 4, h = tid & 15; dst[80 + C + tid] = w2[h * 16 + e]; }
        for (int i = tid; i < 16 * C; i += 256) {
            const int c = i >> 4, h = i & 15;
            dst[336 + C + i] = w3[h * C + c];   // w3t[c][h]
        }
    }
    if (tid == 0) {
        // layout detect: int32 {0,1} has all bytes at (i&3)!=0 equal to 0;
        // random bools do not (P(miss) ~ 2^-48).
        int nz = 0;
        for (int i = 1; i < 64; ++i) if (i & 3) nz |= (int)maskb[i];
        *flagp = (nz != 0) ? 1 : 0;
    }
}

// --------------------------- common prologue macro -------------------------
#define PAIR_PROLOGUE(LDS_SZ, BLOB_OFF)                                        \
    __shared__ float4 sw4[(LDS_SZ) / 4];                                       \
    const int t = blockIdx.x * 256 + threadIdx.x;                              \
    const int n = t >> 5;                                                      \
    const int k = t & 31;                                                      \
    const int j = t;                                                           \
    const int idx = nbr[j];                                                    \
    const float dist = rel[j];                                                 \
    const int bytelay = *flagp;                                                \
    const int mv = bytelay ? (int)maskb[j] : ((const int*)maskb)[j];           \
    stage(sw4, wts + (BLOB_OFF), (LDS_SZ) / 4);                                \
    __syncthreads();                                                           \
    const float* sw = (const float*)sw4;                                       \
    const float mf = mv ? 1.f : 0.f;                                           \
    float cnt = mf;                                                            \
    _Pragma("unroll")                                                          \
    for (int off = 16; off > 0; off >>= 1) cnt += __shfl_xor(cnt, off);        \
    const float inv = 1.f / fmaxf(cnt, 1.f);

#define GATHER_XG0                                                             \
    float xg0[16];                                                             \
    {                                                                          \
        const float4* a = (const float4*)(xj0 + idx * 16);                     \
        const float4* b = (const float4*)(xi0 + n * 16);                       \
        _Pragma("unroll")                                                      \
        for (int q = 0; q < 4; ++q) {                                          \
            const float4 u = a[q], v = b[q];                                   \
            xg0[4 * q + 0] = (u.x + v.x) * mf; xg0[4 * q + 1] = (u.y + v.y) * mf; \
            xg0[4 * q + 2] = (u.z + v.z) * mf; xg0[4 * q + 3] = (u.w + v.w) * mf; \
        }                                                                      \
    }

#define GATHER_XG1                                                             \
    float xg1[8][3];                                                           \
    {                                                                          \
        const float4* a = (const float4*)(xj1 + idx * 24);                     \
        const float4* b = (const float4*)(xi1 + n * 24);                       \
        float tmp[24];                                                         \
        _Pragma("unroll")                                                      \
        for (int q = 0; q < 6; ++q) {                                          \
            const float4 u = a[q], v = b[q];                                   \
            tmp[4 * q + 0] = (u.x + v.x) * mf; tmp[4 * q + 1] = (u.y + v.y) * mf; \
            tmp[4 * q + 2] = (u.z + v.z) * mf; tmp[4 * q + 3] = (u.w + v.w) * mf; \
        }                                                                      \
        _Pragma("unroll")                                                      \
        for (int i = 0; i < 8; ++i)                                            \
            _Pragma("unroll")                                                  \
            for (int m = 0; m < 3; ++m) xg1[i][m] = tmp[i * 3 + m];            \
    }

// ---------------------------------------------------------------------------
// pair 00: di=0,do=0, ci=16, co=8, nf=1 -> o0[0..7]
__global__ __launch_bounds__(256, 2) void k_p00(
    const float* __restrict__ rel, const float* __restrict__ bas,
    const int* __restrict__ nbr, const unsigned char* __restrict__ maskb,
    const float* __restrict__ xi0, const float* __restrict__ xj0,
    const float* __restrict__ wts, const int* __restrict__ flagp,
    float* __restrict__ o0) {
    PAIR_PROLOGUE(SZ00 * 4, BASE00)
    GATHER_XG0
    float hh[16];
    radial16<128>(dist, sw, hh);
    const float Bv = bas[j];
    const float* b3  = sw + 80;
    const float* w3t = sw + 336 + 128;
    float acc[8];
#pragma unroll
    for (int o = 0; o < 8; ++o) acc[o] = 0.f;
#pragma unroll
    for (int i = 0; i < 16; ++i) {
        const float t0 = Bv * xg0[i];
#pragma unroll
        for (int o = 0; o < 8; ++o) {
            const int c = o * 16 + i;
            acc[o] = fmaf(b3[c] + dot16(w3t + c * 16, hh), t0, acc[o]);
        }
    }
#pragma unroll
    for (int off = 16; off > 0; off >>= 1)
#pragma unroll
        for (int o = 0; o < 8; ++o) acc[o] += __shfl_xor(acc[o], off);
    if (k == 0) {
#pragma unroll
        for (int o = 0; o < 8; ++o) o0[n * 16 + o] = acc[o] * inv;
    }
}

// ---------------------------------------------------------------------------
// pair 01: di=0,do=1, ci=16, co=4, nf=1 -> o1[e=0..3]
__global__ __launch_bounds__(256, 2) void k_p01(
    const float* __restrict__ rel, const float* __restrict__ bas,
    const int* __restrict__ nbr, const unsigned char* __restrict__ maskb,
    const float* __restrict__ xi0, const float* __restrict__ xj0,
    const float* __restrict__ wts, const int* __restrict__ flagp,
    float* __restrict__ o1) {
    PAIR_PROLOGUE(SZ01 * 4, BASE01)
    GATHER_XG0
    float hh[16];
    radial16<64>(dist, sw, hh);
    const float* bp = bas + j * 3;
    const float B0 = bp[0], B1 = bp[1], B2 = bp[2];  // over mo
    const float* b3  = sw + 80;
    const float* w3t = sw + 336 + 64;
    float a1[4][3];
#pragma unroll
    for (int o = 0; o < 4; ++o) { a1[o][0] = 0.f; a1[o][1] = 0.f; a1[o][2] = 0.f; }
#pragma unroll
    for (int i = 0; i < 16; ++i) {
        const float x = xg0[i];
#pragma unroll
        for (int o = 0; o < 4; ++o) {
            const int c = o * 16 + i;
            const float rx = (b3[c] + dot16(w3t + c * 16, hh)) * x;
            a1[o][0] = fmaf(rx, B0, a1[o][0]);
            a1[o][1] = fmaf(rx, B1, a1[o][1]);
            a1[o][2] = fmaf(rx, B2, a1[o][2]);
        }
    }
#pragma unroll
    for (int off = 16; off > 0; off >>= 1)
#pragma unroll
        for (int o = 0; o < 4; ++o)
#pragma unroll
            for (int m = 0; m < 3; ++m) a1[o][m] += __shfl_xor(a1[o][m], off);
    if (k == 1) {
#pragma unroll
        for (int o = 0; o < 4; ++o)
#pragma unroll
            for (int m = 0; m < 3; ++m) o1[n * 24 + o * 3 + m] = a1[o][m] * inv;
    }
}

// ---------------------------------------------------------------------------
// pair 10: di=1,do=0, ci=8, co=8, nf=1 -> o0[8..15]
__global__ __launch_bounds__(256, 2) void k_p10(
    const float* __restrict__ rel, const float* __restrict__ bas,
    const int* __restrict__ nbr, const unsigned char* __restrict__ maskb,
    const float* __restrict__ xi1, const float* __restrict__ xj1,
    const float* __restrict__ wts, const int* __restrict__ flagp,
    float* __restrict__ o0) {
    PAIR_PROLOGUE(SZ10 * 4, BASE10)
    GATHER_XG1
    float hh[16];
    radial16<64>(dist, sw, hh);
    const float* bp = bas + j * 3;
    const float B0 = bp[0], B1 = bp[1], B2 = bp[2];  // over mi
    float tx[8];
#pragma unroll
    for (int i = 0; i < 8; ++i)
        tx[i] = fmaf(B2, xg1[i][2], fmaf(B1, xg1[i][1], B0 * xg1[i][0]));
    const float* b3  = sw + 80;
    const float* w3t = sw + 336 + 64;
    float acc[8];
#pragma unroll
    for (int o = 0; o < 8; ++o) acc[o] = 0.f;
#pragma unroll
    for (int i = 0; i < 8; ++i) {
#pragma unroll
        for (int o = 0; o < 8; ++o) {
            const int c = o * 8 + i;
            acc[o] = fmaf(b3[c] + dot16(w3t + c * 16, hh), tx[i], acc[o]);
        }
    }
#pragma unroll
    for (int off = 16; off > 0; off >>= 1)
#pragma unroll
        for (int o = 0; o < 8; ++o) acc[o] += __shfl_xor(acc[o], off);
    if (k == 0) {
#pragma unroll
        for (int o = 0; o < 8; ++o) o0[n * 16 + 8 + o] = acc[o] * inv;
    }
}

// ---------------------------------------------------------------------------
// pair 11: di=1,do=1, ci=8, co=4, nf=3 -> o1[e=4..7]
__global__ __launch_bounds__(256, 2) void k_p11(
    const float* __restrict__ rel, const float* __restrict__ bas,
    const int* __restrict__ nbr, const unsigned char* __restrict__ maskb,
    const float* __restrict__ xi1, const float* __restrict__ xj1,
    const float* __restrict__ wts, const int* __restrict__ flagp,
    float* __restrict__ o1) {
    PAIR_PROLOGUE(SZ11 * 4, BASE11)
    GATHER_XG1
    float hh[16];
    radial16<96>(dist, sw, hh);
    const float* bp = bas + (size_t)j * 27;  // [mo][mi][f]
    const float* b3  = sw + 80;
    const float* w3t = sw + 336 + 96;
    float a1[4][3];
#pragma unroll
    for (int o = 0; o < 4; ++o) { a1[o][0] = 0.f; a1[o][1] = 0.f; a1[o][2] = 0.f; }
#pragma unroll
    for (int f = 0; f < 3; ++f) {
#pragma unroll
        for (int i = 0; i < 8; ++i) {
            const float x0v = xg1[i][0], x1v = xg1[i][1], x2v = xg1[i][2];
            const float t0 = fmaf(bp[2 * 3 + f], x2v, fmaf(bp[1 * 3 + f], x1v, bp[0 * 3 + f] * x0v));
            const float t1 = fmaf(bp[5 * 3 + f], x2v, fmaf(bp[4 * 3 + f], x1v, bp[3 * 3 + f] * x0v));
            const float t2 = fmaf(bp[8 * 3 + f], x2v, fmaf(bp[7 * 3 + f], x1v, bp[6 * 3 + f] * x0v));
#pragma unroll
            for (int o = 0; o < 4; ++o) {
                const int c = (o * 8 + i) * 3 + f;
                const float r = b3[c] + dot16(w3t + c * 16, hh);
                a1[o][0] = fmaf(r, t0, a1[o][0]);
                a1[o][1] = fmaf(r, t1, a1[o][1]);
                a1[o][2] = fmaf(r, t2, a1[o][2]);
            }
        }
    }
#pragma unroll
    for (int off = 16; off > 0; off >>= 1)
#pragma unroll
        for (int o = 0; o < 4; ++o)
#pragma unroll
            for (int m = 0; m < 3; ++m) a1[o][m] += __shfl_xor(a1[o][m], off);
    if (k == 1) {
#pragma unroll
        for (int o = 0; o < 4; ++o)
#pragma unroll
            for (int m = 0; m < 3; ++m) o1[n * 24 + (4 + o) * 3 + m] = a1[o][m] * inv;
    }
}

// ---------------------------------------------------------------------------
__global__ __launch_bounds__(256) void k_out(
    const float* __restrict__ x0, const float* __restrict__ x1,
    const float* __restrict__ i0, const float* __restrict__ i1,
    const float* __restrict__ wo0, const float* __restrict__ wo1,
    const float* __restrict__ ws0, const float* __restrict__ ws1,
    float* __restrict__ out) {
    const int t = blockIdx.x * 256 + threadIdx.x;
    if (t < 131072) {
        const int n = t >> 4, e = t & 15;
        float s = 0.f;
#pragma unroll
        for (int d = 0; d < 16; ++d) {
            s = fmaf(i0[n * 16 + d], wo0[d * 16 + e], s);
            s = fmaf(x0[n * 16 + d], ws0[d * 16 + e], s);
        }
        out[t] = s;
    } else if (t < 327680) {
        const int u = t - 131072;
        const int n = u / 24, r2 = u % 24, e = r2 / 3, m = r2 % 3;
        float s = 0.f;
#pragma unroll
        for (int d = 0; d < 8; ++d) {
            s = fmaf(i1[n * 24 + d * 3 + m], wo1[d * 8 + e], s);
            s = fmaf(x1[n * 24 + d * 3 + m], ws1[d * 8 + e], s);
        }
        out[t] = s;
    }
}

// ---------------------------------------------------------------------------
extern "C" void kernel_launch(void* const* d_in, const int* in_sizes, int n_in,
                              void* d_out, int out_size, void* d_ws, size_t ws_size,
                              hipStream_t stream) {
    const float* x0  = (const float*)d_in[0];
    const float* x1  = (const float*)d_in[1];
    const float* rel = (const float*)d_in[2];
    const float* b00 = (const float*)d_in[3];
    const float* b10 = (const float*)d_in[4];
    const float* b01 = (const float*)d_in[5];
    const float* b11 = (const float*)d_in[6];
    const float* wxi0 = (const float*)d_in[7];
    const float* wxi1 = (const float*)d_in[8];
    const float* wxj0 = (const float*)d_in[9];
    const float* wxj1 = (const float*)d_in[10];
    RPtrs rp;
    for (int i = 0; i < 32; ++i) rp.a[i] = (const float*)d_in[11 + i];
    const float* wo0 = (const float*)d_in[43];
    const float* wo1 = (const float*)d_in[44];
    const float* ws0 = (const float*)d_in[45];
    const float* ws1 = (const float*)d_in[46];
    const int* nbr = (const int*)d_in[47];
    const unsigned char* maskb = (const unsigned char*)d_in[48];

    float* ws = (float*)d_ws;
    float* xi0 = ws + XI0_OFF; float* xj0 = ws + XJ0_OFF;
    float* xi1 = ws + XI1_OFF; float* xj1 = ws + XJ1_OFF;
    float* i0  = ws + INT0_OFF; float* i1 = ws + INT1_OFF;
    float* wts = ws + WTS_OFF;
    int* flagp = (int*)(ws + FLAG_OFF);

    hipLaunchKernelGGL(k_lin_in, dim3(512), dim3(256), 0, stream,
                       x0, x1, wxi0, wxj0, wxi1, wxj1, xi0, xj0, xi1, xj1);
    hipLaunchKernelGGL(k_wts, dim3(1), dim3(256), 0, stream, rp, maskb, wts, flagp);
    hipLaunchKernelGGL(k_p00, dim3(1024), dim3(256), 0, stream,
                       rel, b00, nbr, maskb, xi0, xj0, wts, flagp, i0);
    hipLaunchKernelGGL(k_p01, dim3(1024), dim3(256), 0, stream,
                       rel, b01, nbr, maskb, xi0, xj0, wts, flagp, i1);
    hipLaunchKernelGGL(k_p10, dim3(1024), dim3(256), 0, stream,
                       rel, b10, nbr, maskb, xi1, xj1, wts, flagp, i0);
    hipLaunchKernelGGL(k_p11, dim3(1024), dim3(256), 0, stream,
                       rel, b11, nbr, maskb, xi1, xj1, wts, flagp, i1);
    hipLaunchKernelGGL(k_out, dim3(1280), dim3(256), 0, stream,
                       x0, x1, i0, i1, wo0, wo1, ws0, ws1, (float*)d_out);
}

// Round 8
// 169.576 us; speedup vs baseline: 1.1602x; 1.1602x over previous
//
#include <hip/hip_runtime.h>

// ---------------------------------------------------------------------------
// DTP_5377299055222: SE(3)-equivariant conv block, B=1, N=8192, K=32, H=16
// f32 in / f32 out.
// R7 -> R8: fix compile error (no #pragma inside macro args) — butterflies
// now written inline. Design unchanged from R7:
// (a) correct LDS sizes; (b) 2 lanes per (n,k) pair (lane owns i-half);
// (c) sched_barrier(0) per o-step to stop ds_read hoisting -> no spills.
// ---------------------------------------------------------------------------

#define NNODE 8192
#define KNBR  32

// workspace float offsets
#define XI0_OFF   0         // 8192*16
#define XJ0_OFF   131072
#define XI1_OFF   262144    // 8192*24
#define XJ1_OFF   458752
#define INT0_OFF  655360    // 8192*16
#define INT1_OFF  786432    // 8192*24
#define WTS_OFF   983040    // 7328 floats
#define FLAG_OFF  990400    // 1 int

// radial weight blob per pair: [w1 16][b1 16][g1 16][b2 16][g2 16][b3 C][w2t 256][w3t 16C]
// = 336 + 17C floats.  Order 00,01,10,11 ; C = 128,64,64,96.
#define BASE00 0
#define BASE01 2512
#define BASE10 3936
#define BASE11 5360
#define SZ00 2512
#define SZ01 1424
#define SZ10 1424
#define SZ11 1968

static __device__ __forceinline__ float fsilu(float x) {
    return x * (1.0f / (1.0f + __expf(-x)));
}

static __device__ __forceinline__ float dot16(const float* __restrict__ w, const float* h) {
    const float4* w4 = (const float4*)w;
    float4 a = w4[0], b = w4[1], c = w4[2], d = w4[3];
    float s0 = a.x * h[0];  s0 = fmaf(a.y, h[1], s0);  s0 = fmaf(a.z, h[2],  s0);  s0 = fmaf(a.w, h[3],  s0);
    float s1 = b.x * h[4];  s1 = fmaf(b.y, h[5], s1);  s1 = fmaf(b.z, h[6],  s1);  s1 = fmaf(b.w, h[7],  s1);
    float s2 = c.x * h[8];  s2 = fmaf(c.y, h[9], s2);  s2 = fmaf(c.z, h[10], s2);  s2 = fmaf(c.w, h[11], s2);
    float s3 = d.x * h[12]; s3 = fmaf(d.y, h[13], s3); s3 = fmaf(d.z, h[14], s3);  s3 = fmaf(d.w, h[15], s3);
    return (s0 + s1) + (s2 + s3);
}

static __device__ __forceinline__ void ln16ip(float* x, const float* __restrict__ g) {
    float mu = 0.f;
#pragma unroll
    for (int h = 0; h < 16; ++h) mu += x[h];
    mu *= 0.0625f;
    float var = 0.f;
#pragma unroll
    for (int h = 0; h < 16; ++h) { float d = x[h] - mu; var = fmaf(d, d, var); }
    var *= 0.0625f;
    const float s = rsqrtf(var + 1e-5f);
#pragma unroll
    for (int h = 0; h < 16; ++h) x[h] = (x[h] - mu) * s * g[h];
}

// radial MLP layers 1+2 (incl. both LayerNorms). w = blob base (LDS).
template <int C>
static __device__ __forceinline__ void radial16(float dist, const float* __restrict__ w, float* hh) {
    float t[16];
#pragma unroll
    for (int h = 0; h < 16; ++h) t[h] = fsilu(fmaf(dist, w[h], w[16 + h]));
    ln16ip(t, w + 32);
    const float* w2t = w + 80 + C;
#pragma unroll
    for (int e = 0; e < 16; ++e) hh[e] = fsilu(w[48 + e] + dot16(w2t + e * 16, t));
    ln16ip(hh, w + 64);
}

// stage `cnt4` float4s from src into LDS
static __device__ __forceinline__ void stage(float4* dst, const float* __restrict__ src, int cnt4) {
    const float4* g4 = (const float4*)src;
    for (int i = threadIdx.x; i < cnt4; i += 256) dst[i] = g4[i];
}

// ---------------------------------------------------------------------------
__global__ __launch_bounds__(256) void k_lin_in(
    const float* __restrict__ x0, const float* __restrict__ x1,
    const float* __restrict__ wxi0, const float* __restrict__ wxj0,
    const float* __restrict__ wxi1, const float* __restrict__ wxj1,
    float* __restrict__ xi0, float* __restrict__ xj0,
    float* __restrict__ xi1, float* __restrict__ xj1) {
    const int t = blockIdx.x * 256 + threadIdx.x;  // 131072 threads
    const int n = t >> 4, e = t & 15;
    const float* xr = x0 + n * 16;
    float si = 0.f, sj = 0.f;
#pragma unroll
    for (int d = 0; d < 16; ++d) {
        const float xv = xr[d];
        si = fmaf(xv, wxi0[d * 16 + e], si);
        sj = fmaf(xv, wxj0[d * 16 + e], sj);
    }
    xi0[t] = si; xj0[t] = sj;
    if (e < 8) {
        const float* x1r = x1 + n * 24;
#pragma unroll
        for (int m = 0; m < 3; ++m) {
            float a = 0.f, b = 0.f;
#pragma unroll
            for (int d = 0; d < 8; ++d) {
                const float xv = x1r[d * 3 + m];
                a = fmaf(xv, wxi1[d * 8 + e], a);
                b = fmaf(xv, wxj1[d * 8 + e], b);
            }
            xi1[n * 24 + e * 3 + m] = a;
            xj1[n * 24 + e * 3 + m] = b;
        }
    }
}

// ---------------------------------------------------------------------------
struct RPtrs { const float* a[32]; };  // input order: 00,10,01,11 x (w1,b1,g1,w2,b2,g2,w3,b3)

__global__ void k_wts(RPtrs rp, const unsigned char* __restrict__ maskb,
                      float* __restrict__ wts, int* __restrict__ flagp) {
    const int tid = threadIdx.x;
    const int Cs[4]  = {128, 64, 64, 96};                 // blob order 00,01,10,11
    const int bas[4] = {BASE00, BASE01, BASE10, BASE11};
    const int rpi[4] = {0, 2, 1, 3};                      // d_in group for each blob slot
#pragma unroll
    for (int pp = 0; pp < 4; ++pp) {
        const int C = Cs[pp];
        float* dst = wts + bas[pp];
        const float* w1 = rp.a[rpi[pp] * 8 + 0]; const float* b1 = rp.a[rpi[pp] * 8 + 1];
        const float* g1 = rp.a[rpi[pp] * 8 + 2]; const float* w2 = rp.a[rpi[pp] * 8 + 3];
        const float* b2 = rp.a[rpi[pp] * 8 + 4]; const float* g2 = rp.a[rpi[pp] * 8 + 5];
        const float* w3 = rp.a[rpi[pp] * 8 + 6]; const float* b3 = rp.a[rpi[pp] * 8 + 7];
        if (tid < 16) {
            dst[tid] = w1[tid]; dst[16 + tid] = b1[tid]; dst[32 + tid] = g1[tid];
            dst[48 + tid] = b2[tid]; dst[64 + tid] = g2[tid];
        }
        for (int i = tid; i < C; i += 256) dst[80 + i] = b3[i];
        { const int e = tid >> 4, h = tid & 15; dst[80 + C + tid] = w2[h * 16 + e]; }
        for (int i = tid; i < 16 * C; i += 256) {
            const int c = i >> 4, h = i & 15;
            dst[336 + C + i] = w3[h * C + c];   // w3t[c][h]
        }
    }
    if (tid == 0) {
        // layout detect: int32 {0,1} has all bytes at (i&3)!=0 equal to 0;
        // random bools do not (P(miss) ~ 2^-48).
        int nz = 0;
        for (int i = 1; i < 64; ++i) if (i & 3) nz |= (int)maskb[i];
        *flagp = (nz != 0) ? 1 : 0;
    }
}

// --------------------------- common prologue macro -------------------------
// 2 lanes per pair: t over NNODE*64; n = t>>6, lane6 = t&63, ih = lane6>>5,
// k = lane6&31, j = n*32+k. Lane computes i-half `ih`; butterfly reduces over
// 64 lanes (k and ih).
#define PAIR_PROLOGUE(SZ_FLOATS, BLOB_OFF)                                     \
    __shared__ float4 sw4[(SZ_FLOATS) / 4];                                    \
    const int t = blockIdx.x * 256 + threadIdx.x;                              \
    const int n = t >> 6;                                                      \
    const int lane6 = t & 63;                                                  \
    const int ih = lane6 >> 5;                                                 \
    const int j = n * 32 + (lane6 & 31);                                       \
    const int idx = nbr[j];                                                    \
    const float dist = rel[j];                                                 \
    const int bytelay = *flagp;                                                \
    const int mv = bytelay ? (int)maskb[j] : ((const int*)maskb)[j];           \
    stage(sw4, wts + (BLOB_OFF), (SZ_FLOATS) / 4);                             \
    __syncthreads();                                                           \
    const float* sw = (const float*)sw4;                                       \
    const float mf = mv ? 1.f : 0.f;                                           \
    float cnt = mf;                                                            \
    for (int off = 16; off > 0; off >>= 1) cnt += __shfl_xor(cnt, off);        \
    const float inv = 1.f / fmaxf(cnt, 1.f);

// lane's 8-element half of xg0 (i = ib..ib+7)
#define GATHER_XG0H                                                            \
    const int ib = ih * 8;                                                     \
    float xg0[8];                                                              \
    {                                                                          \
        const float4* a = (const float4*)(xj0 + idx * 16 + ib);                \
        const float4* b = (const float4*)(xi0 + n * 16 + ib);                  \
        for (int q = 0; q < 2; ++q) {                                          \
            const float4 u = a[q], v = b[q];                                   \
            xg0[4 * q + 0] = (u.x + v.x) * mf; xg0[4 * q + 1] = (u.y + v.y) * mf; \
            xg0[4 * q + 2] = (u.z + v.z) * mf; xg0[4 * q + 3] = (u.w + v.w) * mf; \
        }                                                                      \
    }

// lane's 4-row half of xg1 (i = ib..ib+3), 12 floats = 3 float4
#define GATHER_XG1H                                                            \
    const int ib = ih * 4;                                                     \
    float xg1[4][3];                                                           \
    {                                                                          \
        const float4* a = (const float4*)(xj1 + idx * 24 + ib * 3);            \
        const float4* b = (const float4*)(xi1 + n * 24 + ib * 3);              \
        float tmp[12];                                                         \
        for (int q = 0; q < 3; ++q) {                                          \
            const float4 u = a[q], v = b[q];                                   \
            tmp[4 * q + 0] = (u.x + v.x) * mf; tmp[4 * q + 1] = (u.y + v.y) * mf; \
            tmp[4 * q + 2] = (u.z + v.z) * mf; tmp[4 * q + 3] = (u.w + v.w) * mf; \
        }                                                                      \
        for (int i = 0; i < 4; ++i)                                            \
            for (int m = 0; m < 3; ++m) xg1[i][m] = tmp[i * 3 + m];            \
    }

// ---------------------------------------------------------------------------
// pair 00: di=0,do=0, ci=16, co=8, nf=1 -> o0[0..7]
__global__ __launch_bounds__(256, 2) void k_p00(
    const float* __restrict__ rel, const float* __restrict__ bas,
    const int* __restrict__ nbr, const unsigned char* __restrict__ maskb,
    const float* __restrict__ xi0, const float* __restrict__ xj0,
    const float* __restrict__ wts, const int* __restrict__ flagp,
    float* __restrict__ o0) {
    PAIR_PROLOGUE(SZ00, BASE00)
    GATHER_XG0H
    float hh[16];
    radial16<128>(dist, sw, hh);
    const float Bv = bas[j];
    const float* b3  = sw + 80;
    const float* w3t = sw + 336 + 128;
    float acc[8];
#pragma unroll
    for (int o = 0; o < 8; ++o) acc[o] = 0.f;
#pragma unroll
    for (int ii = 0; ii < 8; ++ii) {
        const float t0 = Bv * xg0[ii];
#pragma unroll
        for (int o = 0; o < 8; ++o) {
            const int c = o * 16 + ib + ii;
            acc[o] = fmaf(b3[c] + dot16(w3t + c * 16, hh), t0, acc[o]);
            __builtin_amdgcn_sched_barrier(0);
        }
    }
#pragma unroll
    for (int off = 32; off > 0; off >>= 1) {
#pragma unroll
        for (int o = 0; o < 8; ++o) acc[o] += __shfl_xor(acc[o], off);
    }
    if (lane6 == 0) {
#pragma unroll
        for (int o = 0; o < 8; ++o) o0[n * 16 + o] = acc[o] * inv;
    }
}

// ---------------------------------------------------------------------------
// pair 01: di=0,do=1, ci=16, co=4, nf=1 -> o1[e=0..3]
__global__ __launch_bounds__(256, 2) void k_p01(
    const float* __restrict__ rel, const float* __restrict__ bas,
    const int* __restrict__ nbr, const unsigned char* __restrict__ maskb,
    const float* __restrict__ xi0, const float* __restrict__ xj0,
    const float* __restrict__ wts, const int* __restrict__ flagp,
    float* __restrict__ o1) {
    PAIR_PROLOGUE(SZ01, BASE01)
    GATHER_XG0H
    float hh[16];
    radial16<64>(dist, sw, hh);
    const float* bp = bas + j * 3;
    const float B0 = bp[0], B1 = bp[1], B2 = bp[2];  // over mo
    const float* b3  = sw + 80;
    const float* w3t = sw + 336 + 64;
    float a1[4][3];
#pragma unroll
    for (int o = 0; o < 4; ++o) { a1[o][0] = 0.f; a1[o][1] = 0.f; a1[o][2] = 0.f; }
#pragma unroll
    for (int ii = 0; ii < 8; ++ii) {
        const float x = xg0[ii];
#pragma unroll
        for (int o = 0; o < 4; ++o) {
            const int c = o * 16 + ib + ii;
            const float rx = (b3[c] + dot16(w3t + c * 16, hh)) * x;
            a1[o][0] = fmaf(rx, B0, a1[o][0]);
            a1[o][1] = fmaf(rx, B1, a1[o][1]);
            a1[o][2] = fmaf(rx, B2, a1[o][2]);
            __builtin_amdgcn_sched_barrier(0);
        }
    }
#pragma unroll
    for (int off = 32; off > 0; off >>= 1) {
#pragma unroll
        for (int o = 0; o < 4; ++o) {
#pragma unroll
            for (int m = 0; m < 3; ++m) a1[o][m] += __shfl_xor(a1[o][m], off);
        }
    }
    if (lane6 == 0) {
#pragma unroll
        for (int o = 0; o < 4; ++o) {
#pragma unroll
            for (int m = 0; m < 3; ++m) o1[n * 24 + o * 3 + m] = a1[o][m] * inv;
        }
    }
}

// ---------------------------------------------------------------------------
// pair 10: di=1,do=0, ci=8, co=8, nf=1 -> o0[8..15]
__global__ __launch_bounds__(256, 2) void k_p10(
    const float* __restrict__ rel, const float* __restrict__ bas,
    const int* __restrict__ nbr, const unsigned char* __restrict__ maskb,
    const float* __restrict__ xi1, const float* __restrict__ xj1,
    const float* __restrict__ wts, const int* __restrict__ flagp,
    float* __restrict__ o0) {
    PAIR_PROLOGUE(SZ10, BASE10)
    GATHER_XG1H
    float hh[16];
    radial16<64>(dist, sw, hh);
    const float* bp = bas + j * 3;
    const float B0 = bp[0], B1 = bp[1], B2 = bp[2];  // over mi
    float tx[4];
#pragma unroll
    for (int i = 0; i < 4; ++i)
        tx[i] = fmaf(B2, xg1[i][2], fmaf(B1, xg1[i][1], B0 * xg1[i][0]));
    const float* b3  = sw + 80;
    const float* w3t = sw + 336 + 64;
    float acc[8];
#pragma unroll
    for (int o = 0; o < 8; ++o) acc[o] = 0.f;
#pragma unroll
    for (int ii = 0; ii < 4; ++ii) {
#pragma unroll
        for (int o = 0; o < 8; ++o) {
            const int c = o * 8 + ib + ii;
            acc[o] = fmaf(b3[c] + dot16(w3t + c * 16, hh), tx[ii], acc[o]);
            __builtin_amdgcn_sched_barrier(0);
        }
    }
#pragma unroll
    for (int off = 32; off > 0; off >>= 1) {
#pragma unroll
        for (int o = 0; o < 8; ++o) acc[o] += __shfl_xor(acc[o], off);
    }
    if (lane6 == 0) {
#pragma unroll
        for (int o = 0; o < 8; ++o) o0[n * 16 + 8 + o] = acc[o] * inv;
    }
}

// ---------------------------------------------------------------------------
// pair 11: di=1,do=1, ci=8, co=4, nf=3 -> o1[e=4..7]
__global__ __launch_bounds__(256, 2) void k_p11(
    const float* __restrict__ rel, const float* __restrict__ bas,
    const int* __restrict__ nbr, const unsigned char* __restrict__ maskb,
    const float* __restrict__ xi1, const float* __restrict__ xj1,
    const float* __restrict__ wts, const int* __restrict__ flagp,
    float* __restrict__ o1) {
    PAIR_PROLOGUE(SZ11, BASE11)
    GATHER_XG1H
    float hh[16];
    radial16<96>(dist, sw, hh);
    const float* bp = bas + (size_t)j * 27;  // [mo][mi][f]
    const float* b3  = sw + 80;
    const float* w3t = sw + 336 + 96;
    float a1[4][3];
#pragma unroll
    for (int o = 0; o < 4; ++o) { a1[o][0] = 0.f; a1[o][1] = 0.f; a1[o][2] = 0.f; }
#pragma unroll
    for (int f = 0; f < 3; ++f) {
#pragma unroll
        for (int ii = 0; ii < 4; ++ii) {
            const float x0v = xg1[ii][0], x1v = xg1[ii][1], x2v = xg1[ii][2];
            const float t0 = fmaf(bp[2 * 3 + f], x2v, fmaf(bp[1 * 3 + f], x1v, bp[0 * 3 + f] * x0v));
            const float t1 = fmaf(bp[5 * 3 + f], x2v, fmaf(bp[4 * 3 + f], x1v, bp[3 * 3 + f] * x0v));
            const float t2 = fmaf(bp[8 * 3 + f], x2v, fmaf(bp[7 * 3 + f], x1v, bp[6 * 3 + f] * x0v));
#pragma unroll
            for (int o = 0; o < 4; ++o) {
                const int c = (o * 8 + ib + ii) * 3 + f;
                const float r = b3[c] + dot16(w3t + c * 16, hh);
                a1[o][0] = fmaf(r, t0, a1[o][0]);
                a1[o][1] = fmaf(r, t1, a1[o][1]);
                a1[o][2] = fmaf(r, t2, a1[o][2]);
                __builtin_amdgcn_sched_barrier(0);
            }
        }
    }
#pragma unroll
    for (int off = 32; off > 0; off >>= 1) {
#pragma unroll
        for (int o = 0; o < 4; ++o) {
#pragma unroll
            for (int m = 0; m < 3; ++m) a1[o][m] += __shfl_xor(a1[o][m], off);
        }
    }
    if (lane6 == 0) {
#pragma unroll
        for (int o = 0; o < 4; ++o) {
#pragma unroll
            for (int m = 0; m < 3; ++m) o1[n * 24 + (4 + o) * 3 + m] = a1[o][m] * inv;
        }
    }
}

// ---------------------------------------------------------------------------
__global__ __launch_bounds__(256) void k_out(
    const float* __restrict__ x0, const float* __restrict__ x1,
    const float* __restrict__ i0, const float* __restrict__ i1,
    const float* __restrict__ wo0, const float* __restrict__ wo1,
    const float* __restrict__ ws0, const float* __restrict__ ws1,
    float* __restrict__ out) {
    const int t = blockIdx.x * 256 + threadIdx.x;
    if (t < 131072) {
        const int n = t >> 4, e = t & 15;
        float s = 0.f;
#pragma unroll
        for (int d = 0; d < 16; ++d) {
            s = fmaf(i0[n * 16 + d], wo0[d * 16 + e], s);
            s = fmaf(x0[n * 16 + d], ws0[d * 16 + e], s);
        }
        out[t] = s;
    } else if (t < 327680) {
        const int u = t - 131072;
        const int n = u / 24, r2 = u % 24, e = r2 / 3, m = r2 % 3;
        float s = 0.f;
#pragma unroll
        for (int d = 0; d < 8; ++d) {
            s = fmaf(i1[n * 24 + d * 3 + m], wo1[d * 8 + e], s);
            s = fmaf(x1[n * 24 + d * 3 + m], ws1[d * 8 + e], s);
        }
        out[t] = s;
    }
}

// ---------------------------------------------------------------------------
extern "C" void kernel_launch(void* const* d_in, const int* in_sizes, int n_in,
                              void* d_out, int out_size, void* d_ws, size_t ws_size,
                              hipStream_t stream) {
    const float* x0  = (const float*)d_in[0];
    const float* x1  = (const float*)d_in[1];
    const float* rel = (const float*)d_in[2];
    const float* b00 = (const float*)d_in[3];
    const float* b10 = (const float*)d_in[4];
    const float* b01 = (const float*)d_in[5];
    const float* b11 = (const float*)d_in[6];
    const float* wxi0 = (const float*)d_in[7];
    const float* wxi1 = (const float*)d_in[8];
    const float* wxj0 = (const float*)d_in[9];
    const float* wxj1 = (const float*)d_in[10];
    RPtrs rp;
    for (int i = 0; i < 32; ++i) rp.a[i] = (const float*)d_in[11 + i];
    const float* wo0 = (const float*)d_in[43];
    const float* wo1 = (const float*)d_in[44];
    const float* ws0 = (const float*)d_in[45];
    const float* ws1 = (const float*)d_in[46];
    const int* nbr = (const int*)d_in[47];
    const unsigned char* maskb = (const unsigned char*)d_in[48];

    float* ws = (float*)d_ws;
    float* xi0 = ws + XI0_OFF; float* xj0 = ws + XJ0_OFF;
    float* xi1 = ws + XI1_OFF; float* xj1 = ws + XJ1_OFF;
    float* i0  = ws + INT0_OFF; float* i1 = ws + INT1_OFF;
    float* wts = ws + WTS_OFF;
    int* flagp = (int*)(ws + FLAG_OFF);

    hipLaunchKernelGGL(k_lin_in, dim3(512), dim3(256), 0, stream,
                       x0, x1, wxi0, wxj0, wxi1, wxj1, xi0, xj0, xi1, xj1);
    hipLaunchKernelGGL(k_wts, dim3(1), dim3(256), 0, stream, rp, maskb, wts, flagp);
    // 2 lanes per pair -> NNODE*64 threads -> 2048 blocks of 256
    hipLaunchKernelGGL(k_p00, dim3(2048), dim3(256), 0, stream,
                       rel, b00, nbr, maskb, xi0, xj0, wts, flagp, i0);
    hipLaunchKernelGGL(k_p01, dim3(2048), dim3(256), 0, stream,
                       rel, b01, nbr, maskb, xi0, xj0, wts, flagp, i1);
    hipLaunchKernelGGL(k_p10, dim3(2048), dim3(256), 0, stream,
                       rel, b10, nbr, maskb, xi1, xj1, wts, flagp, i0);
    hipLaunchKernelGGL(k_p11, dim3(2048), dim3(256), 0, stream,
                       rel, b11, nbr, maskb, xi1, xj1, wts, flagp, i1);
    hipLaunchKernelGGL(k_out, dim3(1280), dim3(256), 0, stream,
                       x0, x1, i0, i1, wo0, wo1, ws0, ws1, (float*)d_out);
}

// Round 10
// 111.604 us; speedup vs baseline: 1.7628x; 1.5194x over previous
//
#include <hip/hip_runtime.h>

// ---------------------------------------------------------------------------
// DTP_5377299055222: SE(3)-equivariant conv block, B=1, N=8192, K=32, H=16
// R9 -> R10: fix k_wts2 type-11 w3 staging size typo (16*288 -> 16*96).
// R9's OOB writes scrambled W3TT_11 (-> output-1 absmax 18.3) and overran
// the blob region. Types 00/10 passed -> MFMA layouts/machinery verified.
//   out[o,mo] = sum_{i,f,h} w3[(o,i,f)][h]*V[mo,i,f][h] + b3[(o,i,f)]*U[mo,i,f]
//   V[..][h]  = sum_k (mask*basis*xg)[k][..] * hh[k][h]   <- one 16x16x32 bf16
//   U[..]     = sum_k (mask*basis*xg)[k][..]              <- MFMA (B=ones)
// ---------------------------------------------------------------------------

#define NNODE 8192

// workspace float offsets
#define XI0_OFF   0
#define XJ0_OFF   131072
#define XI1_OFF   262144
#define XJ1_OFF   458752
#define INT0_OFF  655360
#define INT1_OFF  786432
#define WTS2_OFF  983040
#define FLAG_OFF  990640

// blob float offsets: 4x radial blocks (336) then per-type w3/b3 blocks
#define RAD00 0
#define RAD01 336
#define RAD10 672
#define RAD11 1008
#define B3_00   1344
#define W3TT_00 1472   // [16 h][132]  (C=128 +4 pad)
#define B3_01   3584
#define W3TT_01 3648   // [16 h][68]   (C=64 +4)
#define B3_10   4736
#define W3TT_10 4800   // [16 h][68]
#define B3F_11  5888   // [f*32 + (o*8+i)]
#define W3TT_11 5984   // [16 h][100]  ([f*32 + o*8+i] +4)
#define BLOB_N  7584

typedef __attribute__((ext_vector_type(8))) short short8v;
typedef __attribute__((ext_vector_type(4))) float float4v;

static __device__ __forceinline__ float fsilu(float x) {
    return x * (1.0f / (1.0f + __expf(-x)));
}

static __device__ __forceinline__ float dot16(const float* __restrict__ w, const float* h) {
    const float4* w4 = (const float4*)w;
    float4 a = w4[0], b = w4[1], c = w4[2], d = w4[3];
    float s0 = a.x * h[0];  s0 = fmaf(a.y, h[1], s0);  s0 = fmaf(a.z, h[2],  s0);  s0 = fmaf(a.w, h[3],  s0);
    float s1 = b.x * h[4];  s1 = fmaf(b.y, h[5], s1);  s1 = fmaf(b.z, h[6],  s1);  s1 = fmaf(b.w, h[7],  s1);
    float s2 = c.x * h[8];  s2 = fmaf(c.y, h[9], s2);  s2 = fmaf(c.z, h[10], s2);  s2 = fmaf(c.w, h[11], s2);
    float s3 = d.x * h[12]; s3 = fmaf(d.y, h[13], s3); s3 = fmaf(d.z, h[14], s3);  s3 = fmaf(d.w, h[15], s3);
    return (s0 + s1) + (s2 + s3);
}

static __device__ __forceinline__ void ln16ip(float* x, const float* __restrict__ g) {
    float mu = 0.f;
#pragma unroll
    for (int h = 0; h < 16; ++h) mu += x[h];
    mu *= 0.0625f;
    float var = 0.f;
#pragma unroll
    for (int h = 0; h < 16; ++h) { float d = x[h] - mu; var = fmaf(d, d, var); }
    var *= 0.0625f;
    const float s = rsqrtf(var + 1e-5f);
#pragma unroll
    for (int h = 0; h < 16; ++h) x[h] = (x[h] - mu) * s * g[h];
}

// radial MLP layers 1+2 (both LayerNorms). w = radial block base (LDS blob).
static __device__ __forceinline__ void radial16(float dist, const float* __restrict__ w, float* hh) {
    float t[16];
#pragma unroll
    for (int h = 0; h < 16; ++h) t[h] = fsilu(fmaf(dist, w[h], w[16 + h]));
    ln16ip(t, w + 32);
#pragma unroll
    for (int e = 0; e < 16; ++e) hh[e] = fsilu(w[48 + e] + dot16(w + 80 + e * 16, t));
    ln16ip(hh, w + 64);
}

// f32 -> bf16 RNE
static __device__ __forceinline__ short f2b(float x) {
    unsigned u = __float_as_uint(x);
    u += 0x7FFFu + ((u >> 16) & 1u);
    return (short)(u >> 16);
}

// ---------------------------------------------------------------------------
__global__ __launch_bounds__(256) void k_lin_in(
    const float* __restrict__ x0, const float* __restrict__ x1,
    const float* __restrict__ wxi0, const float* __restrict__ wxj0,
    const float* __restrict__ wxi1, const float* __restrict__ wxj1,
    float* __restrict__ xi0, float* __restrict__ xj0,
    float* __restrict__ xi1, float* __restrict__ xj1) {
    const int t = blockIdx.x * 256 + threadIdx.x;
    const int n = t >> 4, e = t & 15;
    const float* xr = x0 + n * 16;
    float si = 0.f, sj = 0.f;
#pragma unroll
    for (int d = 0; d < 16; ++d) {
        const float xv = xr[d];
        si = fmaf(xv, wxi0[d * 16 + e], si);
        sj = fmaf(xv, wxj0[d * 16 + e], sj);
    }
    xi0[t] = si; xj0[t] = sj;
    if (e < 8) {
        const float* x1r = x1 + n * 24;
#pragma unroll
        for (int m = 0; m < 3; ++m) {
            float a = 0.f, b = 0.f;
#pragma unroll
            for (int d = 0; d < 8; ++d) {
                const float xv = x1r[d * 3 + m];
                a = fmaf(xv, wxi1[d * 8 + e], a);
                b = fmaf(xv, wxj1[d * 8 + e], b);
            }
            xi1[n * 24 + e * 3 + m] = a;
            xj1[n * 24 + e * 3 + m] = b;
        }
    }
}

// ---------------------------------------------------------------------------
struct RPtrs { const float* a[32]; };  // d_in order: 00,10,01,11 x (w1,b1,g1,w2,b2,g2,w3,b3)

__global__ void k_wts2(RPtrs rp, const unsigned char* __restrict__ maskb,
                       float* __restrict__ wts, int* __restrict__ flagp) {
    const int tid = threadIdx.x;
    const int radO[4] = {RAD00, RAD01, RAD10, RAD11};
    const int rpi[4]  = {0, 2, 1, 3};                         // d_in group per blob type
#pragma unroll
    for (int pp = 0; pp < 4; ++pp) {
        float* rd = wts + radO[pp];
        const float* w1 = rp.a[rpi[pp] * 8 + 0]; const float* b1 = rp.a[rpi[pp] * 8 + 1];
        const float* g1 = rp.a[rpi[pp] * 8 + 2]; const float* w2 = rp.a[rpi[pp] * 8 + 3];
        const float* b2 = rp.a[rpi[pp] * 8 + 4]; const float* g2 = rp.a[rpi[pp] * 8 + 5];
        if (tid < 16) {
            rd[tid] = w1[tid]; rd[16 + tid] = b1[tid]; rd[32 + tid] = g1[tid];
            rd[48 + tid] = b2[tid]; rd[64 + tid] = g2[tid];
        }
        { const int e = tid >> 4, h = tid & 15; rd[80 + tid] = w2[h * 16 + e]; }  // w2t[e][h]
    }
    // w3 / b3 blocks (h-major w3 with pad per h row)
    {
        const float* w3 = rp.a[0 * 8 + 6]; const float* b3 = rp.a[0 * 8 + 7];  // 00
        for (int i = tid; i < 128; i += 256) wts[B3_00 + i] = b3[i];
        for (int i = tid; i < 16 * 128; i += 256) {
            const int h = i >> 7, c = i & 127;
            wts[W3TT_00 + h * 132 + c] = w3[i];
        }
    }
    {
        const float* w3 = rp.a[2 * 8 + 6]; const float* b3 = rp.a[2 * 8 + 7];  // 01
        for (int i = tid; i < 64; i += 256) wts[B3_01 + i] = b3[i];
        for (int i = tid; i < 16 * 64; i += 256) {
            const int h = i >> 6, c = i & 63;
            wts[W3TT_01 + h * 68 + c] = w3[i];
        }
    }
    {
        const float* w3 = rp.a[1 * 8 + 6]; const float* b3 = rp.a[1 * 8 + 7];  // 10
        for (int i = tid; i < 64; i += 256) wts[B3_10 + i] = b3[i];
        for (int i = tid; i < 16 * 64; i += 256) {
            const int h = i >> 6, c = i & 63;
            wts[W3TT_10 + h * 68 + c] = w3[i];
        }
    }
    {
        const float* w3 = rp.a[3 * 8 + 6]; const float* b3 = rp.a[3 * 8 + 7];  // 11
        for (int i = tid; i < 96; i += 256) {
            const int c8 = i / 3, f = i % 3;
            wts[B3F_11 + f * 32 + c8] = b3[i];
        }
        // w3 is (16, nf*ci*co = 96): h = i/96, cc = i%96, c8 = cc/3, f = cc%3
        for (int i = tid; i < 16 * 96; i += 256) {
            const int h = i / 96, cc = i % 96, c8 = cc / 3, f = cc % 3;
            wts[W3TT_11 + h * 100 + f * 32 + c8] = w3[i];
        }
    }
    if (tid == 0) {
        int nz = 0;
        for (int i = 1; i < 64; ++i) if (i & 3) nz |= (int)maskb[i];
        *flagp = (nz != 0) ? 1 : 0;
    }
}

// ---------------------------------------------------------------------------
// WG = 256 = 4 waves; wave = 2 nodes; WG = 8 nodes.
__global__ __launch_bounds__(256) void k_mfma(
    const float* __restrict__ rel,
    const float* __restrict__ b00, const float* __restrict__ b01,
    const float* __restrict__ b10, const float* __restrict__ b11,
    const int* __restrict__ nbr, const unsigned char* __restrict__ maskb,
    const float* __restrict__ xi0, const float* __restrict__ xj0,
    const float* __restrict__ xi1, const float* __restrict__ xj1,
    const float* __restrict__ wts2, const int* __restrict__ flagp,
    float* __restrict__ o0, float* __restrict__ o1) {
    __shared__ __align__(16) float blob[BLOB_N + 8];
    __shared__ __align__(16) short ybuf[4][3][16][64];   // [wave][slice][m(i)][k2]
    __shared__ __align__(16) short hbuf[4][16][64];      // [wave][h][k2]

    // stage blob once per WG
    {
        const float4* g4 = (const float4*)wts2;
        float4* s4 = (float4*)blob;
        for (int i = threadIdx.x; i < BLOB_N / 4; i += 256) s4[i] = g4[i];
    }
    __syncthreads();

    const int w  = threadIdx.x >> 6;
    const int l  = threadIdx.x & 63;
    const int n0 = blockIdx.x * 8 + w * 2;
    const int nl = n0 + (l >> 5);              // my pair's node
    const int j  = nl * 32 + (l & 31);

    const int idx = nbr[j];
    const float dist = rel[j];
    const int bytelay = *flagp;
    const int mv = bytelay ? (int)maskb[j] : ((const int*)maskb)[j];
    const float mf = mv ? 1.f : 0.f;

    // per-node neighbor count (butterfly within each 32-half)
    float cnt = mf;
#pragma unroll
    for (int off = 16; off > 0; off >>= 1) cnt += __shfl_xor(cnt, off);
    const float inv  = 1.f / fmaxf(cnt, 1.f);
    const float invN0 = __shfl(inv, 0);
    const float invN1 = __shfl(inv, 32);

    // masked gathers
    float xg0[16];
    {
        const float4* a = (const float4*)(xj0 + idx * 16);
        const float4* b = (const float4*)(xi0 + nl * 16);
#pragma unroll
        for (int q = 0; q < 4; ++q) {
            const float4 u = a[q], v = b[q];
            xg0[4 * q + 0] = (u.x + v.x) * mf; xg0[4 * q + 1] = (u.y + v.y) * mf;
            xg0[4 * q + 2] = (u.z + v.z) * mf; xg0[4 * q + 3] = (u.w + v.w) * mf;
        }
    }
    float xg1[8][3];
    {
        const float4* a = (const float4*)(xj1 + idx * 24);
        const float4* b = (const float4*)(xi1 + nl * 24);
        float tmp[24];
#pragma unroll
        for (int q = 0; q < 6; ++q) {
            const float4 u = a[q], v = b[q];
            tmp[4 * q + 0] = (u.x + v.x) * mf; tmp[4 * q + 1] = (u.y + v.y) * mf;
            tmp[4 * q + 2] = (u.z + v.z) * mf; tmp[4 * q + 3] = (u.w + v.w) * mf;
        }
#pragma unroll
        for (int i = 0; i < 8; ++i)
#pragma unroll
            for (int m = 0; m < 3; ++m) xg1[i][m] = tmp[i * 3 + m];
    }

    const int m16 = l & 15;          // A/B row/col for frags; h-index of C col
    const int g4i = l >> 4;          // lane group
    const int rb  = g4i * 4;         // C row base for this lane
    const int ks  = g4i * 8;         // k-offset (shorts) within a node's 32 cols
    const bool rv8 = (g4i < 2);      // valid C rows for 8-row slices
    const bool h0  = (m16 == 0);

    const short one_b = (short)0x3F80;
    const short8v ones = {one_b, one_b, one_b, one_b, one_b, one_b, one_b, one_b};
    const float4v zero4 = {0.f, 0.f, 0.f, 0.f};

    float hh[16];

    // =================== type 00: ci=16, co=8 -> o0[0..7] ===================
    {
        radial16(dist, blob + RAD00, hh);
#pragma unroll
        for (int h = 0; h < 16; ++h) hbuf[w][h][l] = f2b(hh[h]);
        const float Bv = b00[j];
#pragma unroll
        for (int i = 0; i < 16; ++i) ybuf[w][0][i][l] = f2b(Bv * xg0[i]);

        float p[2][8];
#pragma unroll
        for (int a = 0; a < 2; ++a)
#pragma unroll
            for (int o = 0; o < 8; ++o) p[a][o] = 0.f;
#pragma unroll
        for (int h2 = 0; h2 < 2; ++h2) {
            const short8v bfr = *(const short8v*)&hbuf[w][m16][ks + h2 * 32];
            const short8v afr = *(const short8v*)&ybuf[w][0][m16][ks + h2 * 32];
            const float4v V = __builtin_amdgcn_mfma_f32_16x16x32_bf16(afr, bfr, zero4, 0, 0, 0);
            const float4v U = __builtin_amdgcn_mfma_f32_16x16x32_bf16(afr, ones, zero4, 0, 0, 0);
#pragma unroll
            for (int o = 0; o < 8; ++o) {
                const float4 w4 = *(const float4*)&blob[W3TT_00 + m16 * 132 + o * 16 + rb];
                p[h2][o] += w4.x * V[0] + w4.y * V[1] + w4.z * V[2] + w4.w * V[3];
                const float4 bb = *(const float4*)&blob[B3_00 + o * 16 + rb];
                const float du = bb.x * U[0] + bb.y * U[1] + bb.z * U[2] + bb.w * U[3];
                p[h2][o] = h0 ? p[h2][o] + du : p[h2][o];
            }
        }
#pragma unroll
        for (int off = 32; off > 0; off >>= 1)
#pragma unroll
            for (int a = 0; a < 2; ++a)
#pragma unroll
                for (int o = 0; o < 8; ++o) p[a][o] += __shfl_xor(p[a][o], off);
        if (l == 0) {
#pragma unroll
            for (int o = 0; o < 8; ++o) {
                o0[(n0 + 0) * 16 + o] = p[0][o] * invN0;
                o0[(n0 + 1) * 16 + o] = p[1][o] * invN1;
            }
        }
    }

    // =================== type 01: ci=16, co=4, mo=3 -> o1[e=0..3] ===========
    {
        radial16(dist, blob + RAD01, hh);
#pragma unroll
        for (int h = 0; h < 16; ++h) hbuf[w][h][l] = f2b(hh[h]);
        const float* bp = b01 + j * 3;
        const float B0 = bp[0], B1 = bp[1], B2 = bp[2];
#pragma unroll
        for (int i = 0; i < 16; ++i) {
            ybuf[w][0][i][l] = f2b(B0 * xg0[i]);
            ybuf[w][1][i][l] = f2b(B1 * xg0[i]);
            ybuf[w][2][i][l] = f2b(B2 * xg0[i]);
        }
        float p[2][4][3];
#pragma unroll
        for (int a = 0; a < 2; ++a)
#pragma unroll
            for (int o = 0; o < 4; ++o)
#pragma unroll
                for (int m = 0; m < 3; ++m) p[a][o][m] = 0.f;
#pragma unroll
        for (int h2 = 0; h2 < 2; ++h2) {
            const short8v bfr = *(const short8v*)&hbuf[w][m16][ks + h2 * 32];
#pragma unroll
            for (int mo = 0; mo < 3; ++mo) {
                const short8v afr = *(const short8v*)&ybuf[w][mo][m16][ks + h2 * 32];
                const float4v V = __builtin_amdgcn_mfma_f32_16x16x32_bf16(afr, bfr, zero4, 0, 0, 0);
                const float4v U = __builtin_amdgcn_mfma_f32_16x16x32_bf16(afr, ones, zero4, 0, 0, 0);
#pragma unroll
                for (int o = 0; o < 4; ++o) {
                    const float4 w4 = *(const float4*)&blob[W3TT_01 + m16 * 68 + o * 16 + rb];
                    p[h2][o][mo] += w4.x * V[0] + w4.y * V[1] + w4.z * V[2] + w4.w * V[3];
                    const float4 bb = *(const float4*)&blob[B3_01 + o * 16 + rb];
                    const float du = bb.x * U[0] + bb.y * U[1] + bb.z * U[2] + bb.w * U[3];
                    p[h2][o][mo] = h0 ? p[h2][o][mo] + du : p[h2][o][mo];
                }
            }
        }
#pragma unroll
        for (int off = 32; off > 0; off >>= 1)
#pragma unroll
            for (int a = 0; a < 2; ++a)
#pragma unroll
                for (int o = 0; o < 4; ++o)
#pragma unroll
                    for (int m = 0; m < 3; ++m) p[a][o][m] += __shfl_xor(p[a][o][m], off);
        if (l == 0) {
#pragma unroll
            for (int o = 0; o < 4; ++o)
#pragma unroll
                for (int m = 0; m < 3; ++m) {
                    o1[(n0 + 0) * 24 + o * 3 + m] = p[0][o][m] * invN0;
                    o1[(n0 + 1) * 24 + o * 3 + m] = p[1][o][m] * invN1;
                }
        }
    }

    // =================== type 10: ci=8, co=8 -> o0[8..15] ===================
    {
        radial16(dist, blob + RAD10, hh);
#pragma unroll
        for (int h = 0; h < 16; ++h) hbuf[w][h][l] = f2b(hh[h]);
        const float* bp = b10 + j * 3;
        const float B0 = bp[0], B1 = bp[1], B2 = bp[2];
#pragma unroll
        for (int i = 0; i < 8; ++i)
            ybuf[w][0][i][l] = f2b(fmaf(B2, xg1[i][2], fmaf(B1, xg1[i][1], B0 * xg1[i][0])));
        float p[2][8];
#pragma unroll
        for (int a = 0; a < 2; ++a)
#pragma unroll
            for (int o = 0; o < 8; ++o) p[a][o] = 0.f;
#pragma unroll
        for (int h2 = 0; h2 < 2; ++h2) {
            const short8v bfr = *(const short8v*)&hbuf[w][m16][ks + h2 * 32];
            const short8v afr = *(const short8v*)&ybuf[w][0][m16][ks + h2 * 32];
            const float4v V = __builtin_amdgcn_mfma_f32_16x16x32_bf16(afr, bfr, zero4, 0, 0, 0);
            const float4v U = __builtin_amdgcn_mfma_f32_16x16x32_bf16(afr, ones, zero4, 0, 0, 0);
#pragma unroll
            for (int o = 0; o < 8; ++o) {
                const float4 w4 = *(const float4*)&blob[W3TT_10 + m16 * 68 + o * 8 + rb];
                const float dv = w4.x * V[0] + w4.y * V[1] + w4.z * V[2] + w4.w * V[3];
                p[h2][o] = rv8 ? p[h2][o] + dv : p[h2][o];
                const float4 bb = *(const float4*)&blob[B3_10 + o * 8 + rb];
                const float du = bb.x * U[0] + bb.y * U[1] + bb.z * U[2] + bb.w * U[3];
                p[h2][o] = (rv8 && h0) ? p[h2][o] + du : p[h2][o];
            }
        }
#pragma unroll
        for (int off = 32; off > 0; off >>= 1)
#pragma unroll
            for (int a = 0; a < 2; ++a)
#pragma unroll
                for (int o = 0; o < 8; ++o) p[a][o] += __shfl_xor(p[a][o], off);
        if (l == 0) {
#pragma unroll
            for (int o = 0; o < 8; ++o) {
                o0[(n0 + 0) * 16 + 8 + o] = p[0][o] * invN0;
                o0[(n0 + 1) * 16 + 8 + o] = p[1][o] * invN1;
            }
        }
    }

    // =================== type 11: ci=8, co=4, mo,f=3 -> o1[e=4..7] ==========
    {
        radial16(dist, blob + RAD11, hh);
#pragma unroll
        for (int h = 0; h < 16; ++h) hbuf[w][h][l] = f2b(hh[h]);
        const float* bp = b11 + (size_t)j * 27;  // [mo][mi][f]
        float p[2][4][3];
#pragma unroll
        for (int a = 0; a < 2; ++a)
#pragma unroll
            for (int o = 0; o < 4; ++o)
#pragma unroll
                for (int m = 0; m < 3; ++m) p[a][o][m] = 0.f;
#pragma unroll
        for (int mo = 0; mo < 3; ++mo) {
#pragma unroll
            for (int f = 0; f < 3; ++f) {
                const float c0 = bp[mo * 9 + 0 + f], c1 = bp[mo * 9 + 3 + f], c2 = bp[mo * 9 + 6 + f];
#pragma unroll
                for (int i = 0; i < 8; ++i)
                    ybuf[w][f][i][l] = f2b(fmaf(c2, xg1[i][2], fmaf(c1, xg1[i][1], c0 * xg1[i][0])));
            }
#pragma unroll
            for (int h2 = 0; h2 < 2; ++h2) {
                const short8v bfr = *(const short8v*)&hbuf[w][m16][ks + h2 * 32];
#pragma unroll
                for (int f = 0; f < 3; ++f) {
                    const short8v afr = *(const short8v*)&ybuf[w][f][m16][ks + h2 * 32];
                    const float4v V = __builtin_amdgcn_mfma_f32_16x16x32_bf16(afr, bfr, zero4, 0, 0, 0);
                    const float4v U = __builtin_amdgcn_mfma_f32_16x16x32_bf16(afr, ones, zero4, 0, 0, 0);
#pragma unroll
                    for (int o = 0; o < 4; ++o) {
                        const float4 w4 = *(const float4*)&blob[W3TT_11 + m16 * 100 + f * 32 + o * 8 + rb];
                        const float dv = w4.x * V[0] + w4.y * V[1] + w4.z * V[2] + w4.w * V[3];
                        p[h2][o][mo] = rv8 ? p[h2][o][mo] + dv : p[h2][o][mo];
                        const float4 bb = *(const float4*)&blob[B3F_11 + f * 32 + o * 8 + rb];
                        const float du = bb.x * U[0] + bb.y * U[1] + bb.z * U[2] + bb.w * U[3];
                        p[h2][o][mo] = (rv8 && h0) ? p[h2][o][mo] + du : p[h2][o][mo];
                    }
                }
            }
        }
#pragma unroll
        for (int off = 32; off > 0; off >>= 1)
#pragma unroll
            for (int a = 0; a < 2; ++a)
#pragma unroll
                for (int o = 0; o < 4; ++o)
#pragma unroll
                    for (int m = 0; m < 3; ++m) p[a][o][m] += __shfl_xor(p[a][o][m], off);
        if (l == 0) {
#pragma unroll
            for (int o = 0; o < 4; ++o)
#pragma unroll
                for (int m = 0; m < 3; ++m) {
                    o1[(n0 + 0) * 24 + (4 + o) * 3 + m] = p[0][o][m] * invN0;
                    o1[(n0 + 1) * 24 + (4 + o) * 3 + m] = p[1][o][m] * invN1;
                }
        }
    }
}

// ---------------------------------------------------------------------------
__global__ __launch_bounds__(256) void k_out(
    const float* __restrict__ x0, const float* __restrict__ x1,
    const float* __restrict__ i0, const float* __restrict__ i1,
    const float* __restrict__ wo0, const float* __restrict__ wo1,
    const float* __restrict__ ws0, const float* __restrict__ ws1,
    float* __restrict__ out) {
    const int t = blockIdx.x * 256 + threadIdx.x;
    if (t < 131072) {
        const int n = t >> 4, e = t & 15;
        float s = 0.f;
#pragma unroll
        for (int d = 0; d < 16; ++d) {
            s = fmaf(i0[n * 16 + d], wo0[d * 16 + e], s);
            s = fmaf(x0[n * 16 + d], ws0[d * 16 + e], s);
        }
        out[t] = s;
    } else if (t < 327680) {
        const int u = t - 131072;
        const int n = u / 24, r2 = u % 24, e = r2 / 3, m = r2 % 3;
        float s = 0.f;
#pragma unroll
        for (int d = 0; d < 8; ++d) {
            s = fmaf(i1[n * 24 + d * 3 + m], wo1[d * 8 + e], s);
            s = fmaf(x1[n * 24 + d * 3 + m], ws1[d * 8 + e], s);
        }
        out[t] = s;
    }
}

// ---------------------------------------------------------------------------
extern "C" void kernel_launch(void* const* d_in, const int* in_sizes, int n_in,
                              void* d_out, int out_size, void* d_ws, size_t ws_size,
                              hipStream_t stream) {
    const float* x0  = (const float*)d_in[0];
    const float* x1  = (const float*)d_in[1];
    const float* rel = (const float*)d_in[2];
    const float* b00 = (const float*)d_in[3];
    const float* b10 = (const float*)d_in[4];
    const float* b01 = (const float*)d_in[5];
    const float* b11 = (const float*)d_in[6];
    const float* wxi0 = (const float*)d_in[7];
    const float* wxi1 = (const float*)d_in[8];
    const float* wxj0 = (const float*)d_in[9];
    const float* wxj1 = (const float*)d_in[10];
    RPtrs rp;
    for (int i = 0; i < 32; ++i) rp.a[i] = (const float*)d_in[11 + i];
    const float* wo0 = (const float*)d_in[43];
    const float* wo1 = (const float*)d_in[44];
    const float* ws0 = (const float*)d_in[45];
    const float* ws1 = (const float*)d_in[46];
    const int* nbr = (const int*)d_in[47];
    const unsigned char* maskb = (const unsigned char*)d_in[48];

    float* ws = (float*)d_ws;
    float* xi0 = ws + XI0_OFF; float* xj0 = ws + XJ0_OFF;
    float* xi1 = ws + XI1_OFF; float* xj1 = ws + XJ1_OFF;
    float* i0  = ws + INT0_OFF; float* i1 = ws + INT1_OFF;
    float* wts2 = ws + WTS2_OFF;
    int* flagp = (int*)(ws + FLAG_OFF);

    hipLaunchKernelGGL(k_lin_in, dim3(512), dim3(256), 0, stream,
                       x0, x1, wxi0, wxj0, wxi1, wxj1, xi0, xj0, xi1, xj1);
    hipLaunchKernelGGL(k_wts2, dim3(1), dim3(256), 0, stream, rp, maskb, wts2, flagp);
    hipLaunchKernelGGL(k_mfma, dim3(1024), dim3(256), 0, stream,
                       rel, b00, b01, b10, b11, nbr, maskb,
                       xi0, xj0, xi1, xj1, wts2, flagp, i0, i1);
    hipLaunchKernelGGL(k_out, dim3(1280), dim3(256), 0, stream,
                       x0, x1, i0, i1, wo0, wo1, ws0, ws1, (float*)d_out);
}